// Round 10
// baseline (414.939 us; speedup 1.0000x reference)
//
#include <hip/hip_runtime.h>
#include <cstdint>
#include <cstddef>

#define N_PTS 50000
#define H 16
#define CIN 256
#define C 256
#define CPG 32
#define CR 64

typedef short bf16x8 __attribute__((ext_vector_type(8)));
typedef float f32x4 __attribute__((ext_vector_type(4)));

// Native bf16 convert (r7-verified: 1 VALU op, RNE).
__device__ __forceinline__ unsigned short f2bf(float f) {
    __bf16 b = (__bf16)f;
    return __builtin_bit_cast(unsigned short, b);
}
__device__ __forceinline__ float bf2f(unsigned short s) {
    return __uint_as_float(((unsigned int)s) << 16);
}

// ---------------------------------------------------------------------------
// Prep v2: ONLY weight-fragment packing (109 blocks). The s_feats bf16
// conversion is gone -- gemm v4 reads f32 feats directly (L3-resident) and
// converts in-register. [0,96): Wq|Wk|Wv frags; [96,109): Wd2/Wa1/Wa2 frags.
//   frag(kt,nt): lane l holds B[kt*32+(l>>4)*8+j][nt*16+(l&15)], j=0..7
// ---------------------------------------------------------------------------
__global__ __launch_bounds__(256) void prep_all(
    const float* __restrict__ Wq, const float* __restrict__ Wk,
    const float* __restrict__ Wv,
    const float* __restrict__ Wd2, const float* __restrict__ Wa1,
    const float* __restrict__ Wa2,
    unsigned short* __restrict__ gemmFrags,
    unsigned short* __restrict__ attnFrags)
{
    int bid = blockIdx.x;
    if (bid < 96) {
        int t = bid * 256 + threadIdx.x;             // 0..24575
        int lane = t & 63;
        int f = t >> 6;                              // kt*48 + ntg
        int ntg = f % 48;
        const float* W = ntg < 16 ? Wq : (ntg < 32 ? Wk : Wv);
        int colc = (ntg & 15) * 16 + (lane & 15);
        int row0 = (f / 48) * 32 + ((lane >> 4) << 3);
        unsigned short tmp[8];
        #pragma unroll
        for (int j = 0; j < 8; ++j) tmp[j] = f2bf(W[(size_t)(row0 + j) * 256 + colc]);
        *(bf16x8*)&gemmFrags[(size_t)t * 8] = *(bf16x8*)tmp;
    } else {
        int t = (bid - 96) * 256 + threadIdx.x;
        if (t >= 3200) return;
        const float* W; int Nc, NT, loc, base;
        if (t < 2048)      { W = Wd2; Nc = 256; NT = 16; loc = t;        base = 0; }
        else if (t < 3072) { W = Wa1; Nc = 32;  NT = 2;  loc = t - 2048; base = 16384; }
        else               { W = Wa2; Nc = 32;  NT = 2;  loc = t - 3072; base = 24576; }
        int f = loc >> 6, lane = loc & 63;
        int kt = f / NT, nt = f - kt * NT;
        int colc = nt * 16 + (lane & 15);
        int row0 = kt * 32 + ((lane >> 4) << 3);
        unsigned short tmp[8];
        #pragma unroll
        for (int j = 0; j < 8; ++j) tmp[j] = f2bf(W[(size_t)(row0 + j) * Nc + colc]);
        *(bf16x8*)&attnFrags[(size_t)(base + loc * 8)] = *(bf16x8*)tmp;
    }
}

// ---------------------------------------------------------------------------
// QKV GEMM v4: kv-PAIRED blocks + direct f32 A reads.
// The residual (~190us) survived 3 inner-loop rewrites; the invariant was the
// epilogue: k and v interleave slots (256+2c / 257+2c) were owned by
// DIFFERENT blocks -> 51.2MB of 2-byte stores with 2-byte holes.
// v4 grid bx: 0,1 = q col-halves (unchanged); 2..5 = (k AND v) for one 64-col
// quarter each (nt 0-3 = k, nt 4-7 = v; acc footprint identical). Epilogue
// packs (v<<16)|k into ONE coalesced dword store -- adjacent lanes hit
// adjacent dwords, zero holes, half the store instructions.
// Layout written is byte-identical to v3's: dword[128+c] = (k[c], v[c]).
// A: reads s_feats f32 directly (L3-resident, 51.2MB), converts in-register
// (8 cvt per 16 MFMAs) -> prep's 77MB conversion pass eliminated.
// ---------------------------------------------------------------------------
__global__ __launch_bounds__(256) void qkv_gemm_mfma(
    const float* __restrict__ feats,            // [N][256] f32
    const unsigned short* __restrict__ wfrags,
    const float* __restrict__ bq, const float* __restrict__ bk,
    const float* __restrict__ bv, unsigned short* __restrict__ out)
{
    __shared__ unsigned short s_b[64 * 64 * 8];   // 64KB
    const int tid = threadIdx.x;
    const int lane = tid & 63, wave = tid >> 6;
    const int quad = lane >> 4, col16 = lane & 15;
    const int bx = blockIdx.x, by = blockIdx.y;
    const bool kvmode = bx >= 2;
    const int qd = bx - 2;                        // kv quarter (when kvmode)

    // ---- stage B-tile: 4096 x 16B chunks; nt->ntg mapping per block mode
    #pragma unroll
    for (int i = 0; i < 16; ++i) {
        int ci = i * 256 + tid;
        int f = ci >> 6, w = ci & 63;
        int kt = f >> 3, nt = f & 7;
        int ntg = !kvmode ? (bx * 8 + nt)
                          : (nt < 4 ? (16 + qd * 4 + nt) : (32 + qd * 4 + nt - 4));
        *(bf16x8*)&s_b[(size_t)ci * 8] =
            *(const bf16x8*)&wfrags[((size_t)(kt * 48 + ntg) * 64 + w) * 8];
    }

    int r0 = by * 128 + wave * 32 + col16;
    int r1 = r0 + 16;
    r0 = r0 < N_PTS ? r0 : N_PTS - 1;
    r1 = r1 < N_PTS ? r1 : N_PTS - 1;
    const float* a0p = &feats[(size_t)r0 * 256 + quad * 8];
    const float* a1p = &feats[(size_t)r1 * 256 + quad * 8];

    f32x4 acc[2][8] = {};
    __syncthreads();

    #pragma unroll 2
    for (int kt = 0; kt < 8; ++kt) {
        float4 f00 = *(const float4*)(a0p + kt * 32);
        float4 f01 = *(const float4*)(a0p + kt * 32 + 4);
        float4 f10 = *(const float4*)(a1p + kt * 32);
        float4 f11 = *(const float4*)(a1p + kt * 32 + 4);
        unsigned short t0[8] = {f2bf(f00.x), f2bf(f00.y), f2bf(f00.z), f2bf(f00.w),
                                f2bf(f01.x), f2bf(f01.y), f2bf(f01.z), f2bf(f01.w)};
        unsigned short t1[8] = {f2bf(f10.x), f2bf(f10.y), f2bf(f10.z), f2bf(f10.w),
                                f2bf(f11.x), f2bf(f11.y), f2bf(f11.z), f2bf(f11.w)};
        bf16x8 af0 = *(bf16x8*)t0;
        bf16x8 af1 = *(bf16x8*)t1;
        #pragma unroll
        for (int nt = 0; nt < 8; ++nt) {
            bf16x8 bf = *(bf16x8*)&s_b[((kt * 8 + nt) * 64 + lane) * 8];
            acc[0][nt] = __builtin_amdgcn_mfma_f32_16x16x32_bf16(af0, bf, acc[0][nt], 0, 0, 0);
            acc[1][nt] = __builtin_amdgcn_mfma_f32_16x16x32_bf16(af1, bf, acc[1][nt], 0, 0, 0);
        }
    }

    if (!kvmode) {
        // q: shorts [0..255], contiguous 2B stores (adjacent lanes adjacent)
        #pragma unroll
        for (int nt = 0; nt < 8; ++nt) {
            int cIn = bx * 128 + nt * 16 + col16;
            float bb = bq[cIn];
            #pragma unroll
            for (int mt = 0; mt < 2; ++mt) {
                #pragma unroll
                for (int r = 0; r < 4; ++r) {
                    int row = by * 128 + wave * 32 + mt * 16 + quad * 4 + r;
                    if (row < N_PTS)
                        out[(size_t)row * 768 + cIn] = f2bf(acc[mt][nt][r] + bb);
                }
            }
        }
    } else {
        // kv: dword[128+cIn] = k[cIn] | v[cIn]<<16  (coalesced, no holes)
        unsigned int* out32 = (unsigned int*)out;
        #pragma unroll
        for (int nt = 0; nt < 4; ++nt) {
            int cIn = qd * 64 + nt * 16 + col16;
            float bbk = bk[cIn], bbv = bv[cIn];
            #pragma unroll
            for (int mt = 0; mt < 2; ++mt) {
                #pragma unroll
                for (int r = 0; r < 4; ++r) {
                    int row = by * 128 + wave * 32 + mt * 16 + quad * 4 + r;
                    if (row < N_PTS) {
                        unsigned int kk = f2bf(acc[mt][nt][r] + bbk);
                        unsigned int vv = f2bf(acc[mt][nt + 4][r] + bbv);
                        out32[(size_t)row * 384 + 128 + cIn] = kk | (vv << 16);
                    }
                }
            }
        }
    }
}

// ---------------------------------------------------------------------------
// Fused attention == r7 v3 structure EXACTLY (verified 212.4 us, absmax
// 0.03125). r9's bf16-pg experiment reverted: LDS shrink did NOT raise
// occupancy (pinned ~11-12 waves/CU by an unidentified limit) and the extra
// converts cost 6%. attn is at its structural floor for this decomposition;
// all further work targets the prep/gemm residual.
// ---------------------------------------------------------------------------
#define D1S 72
#define PGS 66      // private geom row stride (dwords): 2-way banks on rd & wr
#define QKS 264
#define A1S 40
#define A2S 33

__global__ __launch_bounds__(256) void attn_mfma(
    const unsigned short* __restrict__ qkv,     // [N][768] q | kv-interleaved
    const float* __restrict__ q_pts, const float* __restrict__ s_pts,
    const int* __restrict__ nbr,
    const float* __restrict__ Wd1, const float* __restrict__ bd1,
    const float* __restrict__ bd2,
    const unsigned short* __restrict__ frags,
    const float* __restrict__ ba1, const float* __restrict__ ba2,
    float* __restrict__ out)
{
    __shared__ unsigned short s_d1[H * D1S];
    __shared__ float          s_pg[4 * H * PGS];   // wave-private geom tiles
    __shared__ unsigned short s_qk[H * QKS];
    __shared__ unsigned short s_a1[H * A1S];
    __shared__ float          s_a2[H * A2S];
    __shared__ float          s_rel[4][H][3];
    __shared__ int            s_idx[4][H];

    const int tid = threadIdx.x;
    const int lane = tid & 63, wave = tid >> 6;
    const int quad = lane >> 4, col = lane & 15;
    const int n0 = blockIdx.x * 4;
    const int c = tid;                 // == wave*64 + lane

    if (tid < 64) {
        int pp = tid >> 4, hh = tid & 15;
        int idx = nbr[(size_t)(n0 + pp) * H + hh];
        s_idx[pp][hh] = idx;
        #pragma unroll
        for (int x = 0; x < 3; ++x)
            s_rel[pp][hh][x] = s_pts[(size_t)idx * 3 + x] - q_pts[(size_t)(n0 + pp) * 3 + x];
    }

    const float w1x = Wd1[lane], w1y = Wd1[64 + lane], w1z = Wd1[128 + lane];
    const float b1 = bd1[lane];
    const float b2 = bd2[c];
    bf16x8 wd2f[2][4];
    #pragma unroll
    for (int t = 0; t < 4; ++t) {
        wd2f[0][t] = *(const bf16x8*)&frags[((size_t)((0 * 16 + wave * 4 + t) * 64 + lane)) * 8];
        wd2f[1][t] = *(const bf16x8*)&frags[((size_t)((1 * 16 + wave * 4 + t) * 64 + lane)) * 8];
    }
    bf16x8 wa1f[8];
    bf16x8 wa2f = {0,0,0,0,0,0,0,0};
    if (wave < 2) {
        #pragma unroll
        for (int kt = 0; kt < 8; ++kt)
            wa1f[kt] = *(const bf16x8*)&frags[16384 + ((size_t)((kt * 2 + wave) * 64 + lane)) * 8];
        wa2f = *(const bf16x8*)&frags[24576 + ((size_t)(wave * 64 + lane)) * 8];
    }
    __syncthreads();

    float* pg = &s_pg[wave * (H * PGS)];

    for (int p = 0; p < 4; ++p) {
        const int n = n0 + p;

        // d1 = lrelu(rel @ Wd1 + bd1)  (cross-wave, needs the barrier below)
        #pragma unroll
        for (int pass = 0; pass < 4; ++pass) {
            int h = pass * 4 + wave;
            float v = b1 + s_rel[p][h][0] * w1x + s_rel[p][h][1] * w1y + s_rel[p][h][2] * w1z;
            s_d1[h * D1S + lane] = f2bf(fmaxf(v, 0.1f * v));
        }
        __syncthreads();

        // ---- issue all gathers now; no barrier until after they're consumed
        unsigned int u[H];
        #pragma unroll
        for (int h = 0; h < H; ++h)
            u[h] = *(const unsigned int*)&qkv[(size_t)s_idx[p][h] * 768 + 256 + 2 * c];
        float qf = bf2f(qkv[(size_t)s_idx[p][0] * 768 + c]);

        // geom = d1 @ Wd2 (16x64 @ 64x256) -> wave-private C-tile in LDS
        {
            bf16x8 ga = *(bf16x8*)&s_d1[col * D1S + quad * 8];
            bf16x8 gb = *(bf16x8*)&s_d1[col * D1S + 32 + quad * 8];
            #pragma unroll
            for (int t = 0; t < 4; ++t) {
                f32x4 acc = {0.f, 0.f, 0.f, 0.f};
                acc = __builtin_amdgcn_mfma_f32_16x16x32_bf16(ga, wd2f[0][t], acc, 0, 0, 0);
                acc = __builtin_amdgcn_mfma_f32_16x16x32_bf16(gb, wd2f[1][t], acc, 0, 0, 0);
                #pragma unroll
                for (int rr = 0; rr < 4; ++rr)
                    pg[(quad * 4 + rr) * PGS + t * 16 + col] = acc[rr];
            }
        }
        // same-wave ds_write -> ds_read: lgkmcnt only, NO __syncthreads here.

        // elementwise: consume gathered kv + private geom; build vg + qk
        float vg[H];
        #pragma unroll
        for (int h = 0; h < H; ++h) {
            float g = pg[h * PGS + lane] + b2;
            float nk = __uint_as_float(u[h] << 16);
            float nv = __uint_as_float(u[h] & 0xffff0000u);
            vg[h] = nv - g;
            float tq = qf - nk - g;
            s_qk[h * QKS + c] = f2bf(fmaxf(tq, 0.1f * tq));
        }
        __syncthreads();

        // a1 = lrelu(qk @ Wa1 + ba1) on waves 0,1
        if (wave < 2) {
            f32x4 acc = {0.f, 0.f, 0.f, 0.f};
            #pragma unroll
            for (int kt = 0; kt < 8; ++kt) {
                bf16x8 a = *(bf16x8*)&s_qk[col * QKS + kt * 32 + quad * 8];
                acc = __builtin_amdgcn_mfma_f32_16x16x32_bf16(a, wa1f[kt], acc, 0, 0, 0);
            }
            int j = wave * 16 + col;
            float bb = ba1[j];
            #pragma unroll
            for (int rr = 0; rr < 4; ++rr) {
                float v = acc[rr] + bb;
                s_a1[(quad * 4 + rr) * A1S + j] = f2bf(fmaxf(v, 0.1f * v));
            }
        }
        __syncthreads();

        // a2 = a1 @ Wa2 + ba2 on waves 0,1
        if (wave < 2) {
            bf16x8 aa = *(bf16x8*)&s_a1[col * A1S + quad * 8];
            f32x4 acc = {0.f, 0.f, 0.f, 0.f};
            acc = __builtin_amdgcn_mfma_f32_16x16x32_bf16(aa, wa2f, acc, 0, 0, 0);
            int j = wave * 16 + col;
            float bb = ba2[j];
            #pragma unroll
            for (int rr = 0; rr < 4; ++rr)
                s_a2[(quad * 4 + rr) * A2S + j] = acc[rr] + bb;
        }
        __syncthreads();

        // softmax over h, wave 0
        if (wave == 0) {
            int j = lane & 31, hb = (lane >> 5) * 8;
            float vals[8];
            float mx = -1e30f;
            #pragma unroll
            for (int i = 0; i < 8; ++i) {
                vals[i] = s_a2[(hb + i) * A2S + j];
                mx = fmaxf(mx, vals[i]);
            }
            mx = fmaxf(mx, __shfl_xor(mx, 32));
            float sum = 0.f;
            #pragma unroll
            for (int i = 0; i < 8; ++i) { vals[i] = __expf(vals[i] - mx); sum += vals[i]; }
            sum += __shfl_xor(sum, 32);
            float inv = 1.f / sum;
            #pragma unroll
            for (int i = 0; i < 8; ++i) s_a2[(hb + i) * A2S + j] = vals[i] * inv;
        }
        __syncthreads();

        // out[n][c] = sum_h vg[h] * attn[h][c>>3]
        float o = 0.f;
        const int aj = c >> 3;
        #pragma unroll
        for (int h = 0; h < H; ++h) o += vg[h] * s_a2[h * A2S + aj];
        out[(size_t)n * C + c] = o;
    }
}

// ---------------------------------------------------------------------------

extern "C" void kernel_launch(void* const* d_in, const int* in_sizes, int n_in,
                              void* d_out, int out_size, void* d_ws, size_t ws_size,
                              hipStream_t stream) {
    const float* q_pts   = (const float*)d_in[0];
    const float* s_pts   = (const float*)d_in[1];
    const float* s_feats = (const float*)d_in[2];
    const int*   nbr     = (const int*)d_in[3];
    const float* Wq  = (const float*)d_in[4];
    const float* bq  = (const float*)d_in[5];
    const float* Wk  = (const float*)d_in[6];
    const float* bk  = (const float*)d_in[7];
    const float* Wv  = (const float*)d_in[8];
    const float* bv  = (const float*)d_in[9];
    const float* Wd1 = (const float*)d_in[10];
    const float* bd1 = (const float*)d_in[11];
    const float* Wd2 = (const float*)d_in[12];
    const float* bd2 = (const float*)d_in[13];
    const float* Wa1 = (const float*)d_in[14];
    const float* ba1 = (const float*)d_in[15];
    const float* Wa2 = (const float*)d_in[16];
    const float* ba2 = (const float*)d_in[17];

    float* out = (float*)d_out;
    char* ws = (char*)d_ws;
    unsigned short* qkvb      = (unsigned short*)(ws + 25600000);      // 76.8 MB
    unsigned short* attnFrags = (unsigned short*)(ws + 102400000);     // 51.2 KB
    unsigned short* gemmFrags = (unsigned short*)(ws + 102451200);     // 384 KB

    prep_all<<<109, 256, 0, stream>>>(Wq, Wk, Wv, Wd2, Wa1, Wa2,
                                      gemmFrags, attnFrags);

    dim3 g1(6, (N_PTS + 127) / 128);
    qkv_gemm_mfma<<<g1, 256, 0, stream>>>(s_feats, gemmFrags, bq, bk, bv, qkvb);

    attn_mfma<<<(N_PTS / 4), 256, 0, stream>>>(qkvb, q_pts, s_pts, nbr,
                                               Wd1, bd1, bd2, attnFrags,
                                               ba1, ba2, out);
}

// Round 11
// 375.748 us; speedup vs baseline: 1.1043x; 1.1043x over previous
//
#include <hip/hip_runtime.h>
#include <cstdint>
#include <cstddef>

#define N_PTS 50000
#define H 16
#define CIN 256
#define C 256
#define CPG 32
#define CR 64

typedef short bf16x8 __attribute__((ext_vector_type(8)));
typedef float f32x4 __attribute__((ext_vector_type(4)));

// Native bf16 convert (r7-verified: 1 VALU op, RNE).
__device__ __forceinline__ unsigned short f2bf(float f) {
    __bf16 b = (__bf16)f;
    return __builtin_bit_cast(unsigned short, b);
}
__device__ __forceinline__ float bf2f(unsigned short s) {
    return __uint_as_float(((unsigned int)s) << 16);
}

// Raw barrier: drain only LDS (lgkmcnt), NOT vmcnt -> next-K global loads
// stay in flight across the barrier. Correctness verified r3/r4 (absmax
// unchanged). All cross-wave handoffs in the K-loop are via LDS.
#define LBAR() do { asm volatile("s_waitcnt lgkmcnt(0)" ::: "memory"); \
                    __builtin_amdgcn_s_barrier();                      \
                    asm volatile("" ::: "memory"); } while (0)

// ---------------------------------------------------------------------------
// Prep v3: [0,6250) convert s_feats -> FRAGMENT-ORDERED bf16 A
//   (A-frag f = R2*8+kt, lane l: row = R2*16+(l&15), col = kt*32+(l>>4)*8+j);
// [6250,6346) pack Wq|Wk|Wv B-frags (unchanged layout);
// [6346,6359) pack Wd2/Wa1/Wa2 frags (unchanged).
// ---------------------------------------------------------------------------
__global__ __launch_bounds__(256) void prep_all(
    const float* __restrict__ feats,
    const float* __restrict__ Wq, const float* __restrict__ Wk,
    const float* __restrict__ Wv,
    const float* __restrict__ Wd2, const float* __restrict__ Wa1,
    const float* __restrict__ Wa2,
    unsigned short* __restrict__ Afrag,
    unsigned short* __restrict__ gemmFrags,
    unsigned short* __restrict__ attnFrags)
{
    int bid = blockIdx.x;
    if (bid < 6250) {
        int t = bid * 256 + threadIdx.x;     // 1.6M lane-slots = 3125*8*64
        int lane = t & 63, f = t >> 6;       // f = R2*8 + kt
        int R2 = f >> 3, kt = f & 7;
        int row = R2 * 16 + (lane & 15);
        int col = kt * 32 + ((lane >> 4) << 3);
        const float* s = &feats[(size_t)row * 256 + col];
        float4 f0 = *(const float4*)s;
        float4 f1 = *(const float4*)(s + 4);
        unsigned short tmp[8] = {f2bf(f0.x), f2bf(f0.y), f2bf(f0.z), f2bf(f0.w),
                                 f2bf(f1.x), f2bf(f1.y), f2bf(f1.z), f2bf(f1.w)};
        *(bf16x8*)&Afrag[(size_t)t * 8] = *(bf16x8*)tmp;
    } else if (bid < 6346) {
        int t = (bid - 6250) * 256 + threadIdx.x;   // 0..24575
        int lane = t & 63;
        int f = t >> 6;                              // kt*48 + ntg
        int ntg = f % 48;
        const float* W = ntg < 16 ? Wq : (ntg < 32 ? Wk : Wv);
        int colc = (ntg & 15) * 16 + (lane & 15);
        int row0 = (f / 48) * 32 + ((lane >> 4) << 3);
        unsigned short tmp[8];
        #pragma unroll
        for (int j = 0; j < 8; ++j) tmp[j] = f2bf(W[(size_t)(row0 + j) * 256 + colc]);
        *(bf16x8*)&gemmFrags[(size_t)t * 8] = *(bf16x8*)tmp;
    } else {
        int t = (bid - 6346) * 256 + threadIdx.x;
        if (t >= 3200) return;
        const float* W; int Nc, NT, loc, base;
        if (t < 2048)      { W = Wd2; Nc = 256; NT = 16; loc = t;        base = 0; }
        else if (t < 3072) { W = Wa1; Nc = 32;  NT = 2;  loc = t - 2048; base = 16384; }
        else               { W = Wa2; Nc = 32;  NT = 2;  loc = t - 3072; base = 24576; }
        int f = loc >> 6, lane = loc & 63;
        int kt = f / NT, nt = f - kt * NT;
        int colc = nt * 16 + (lane & 15);
        int row0 = kt * 32 + ((lane >> 4) << 3);
        unsigned short tmp[8];
        #pragma unroll
        for (int j = 0; j < 8; ++j) tmp[j] = f2bf(W[(size_t)(row0 + j) * Nc + colc]);
        *(bf16x8*)&attnFrags[(size_t)(base + loc * 8)] = *(bf16x8*)tmp;
    }
}

// ---------------------------------------------------------------------------
// QKV GEMM v5 -- ladder-conformant structure (m90/m97 class).
// Residual accounting (r10): prep ~5us, attn 213 -> gemm ~195us = ~110 TF,
// the naive-structure tier. All prior variants shared: transposed
// direct-global A on the critical path + single-stage barriers. v5:
//  - A AND B fragment-ordered in global; staging = coalesced 16B/lane reads.
//  - single 16KB LDS buffer; reg-staged double "buffer" in VGPRs: loads for
//    kt+1 issue before the lgkmcnt-only barrier and stay in flight across it.
//  - LBAR (not __syncthreads) -> no vmcnt drain in the K-loop.
//  - 2x2 wave split, 4x4 frag acc (64 VGPR) per wave.
//  - kv-paired epilogue (r10-verified layout): dword[128+c] = k[c]|v[c]<<16.
// grid bx: 0,1 = q col-halves; 2..5 = kv quarter qd (nt even=k, odd=v).
// ---------------------------------------------------------------------------
__global__ __launch_bounds__(256) void qkv_gemm_mfma(
    const unsigned short* __restrict__ Afrag,   // [3125*8][64][8] frag-ordered
    const unsigned short* __restrict__ wfrags,
    const float* __restrict__ bq, const float* __restrict__ bk,
    const float* __restrict__ bv, unsigned short* __restrict__ out)
{
    __shared__ unsigned short s_ab[16 * 64 * 8];   // 16 KB: chunks 0-7 A, 8-15 B
    const int tid = threadIdx.x;
    const int lane = tid & 63, wave = tid >> 6;
    const int quad = lane >> 4, col16 = lane & 15;
    const int wr = wave >> 1, wc = wave & 1;
    const int bx = blockIdx.x, by = blockIdx.y;
    const bool kvmode = bx >= 2;
    const int qd = bx - 2;

    // this thread's 4 staging chunks: c = wave*4+i (0-7 A, 8-15 B)
    const unsigned short* srcp[4];
    #pragma unroll
    for (int i = 0; i < 4; ++i) {
        int c = wave * 4 + i;
        if (c < 8) {
            int R2 = by * 8 + c;                 // 16-row group
            R2 = R2 < 3125 ? R2 : 3124;          // clamp OOB (store-guarded)
            srcp[i] = &Afrag[(((size_t)R2 * 8) * 64 + lane) * 8];   // +kt*512
        } else {
            int nt = c - 8;
            int ntg;
            if (!kvmode) ntg = bx * 8 + nt;
            else {
                int cf = nt >> 1;
                ntg = ((nt & 1) ? 32 : 16) + qd * 4 + cf;
            }
            srcp[i] = &wfrags[((size_t)ntg * 64 + lane) * 8];       // +kt*24576
        }
    }
    const int sstep = (wave < 2) ? 512 : 24576;  // per-kt source advance (shorts)
    unsigned short* dstp = &s_ab[((wave * 4) * 64 + lane) * 8];
    const unsigned short* afp = &s_ab[((wr * 4) * 64 + lane) * 8];
    const unsigned short* bfp = &s_ab[((8 + wc * 4) * 64 + lane) * 8];

    bf16x8 cur[4], nxt[4];
    #pragma unroll
    for (int i = 0; i < 4; ++i) cur[i] = *(const bf16x8*)(srcp[i]);

    f32x4 acc[4][4] = {};

    #pragma unroll
    for (int kt = 0; kt < 8; ++kt) {
        // write this K-step's chunks (vmcnt dependency on cur auto-inserted)
        #pragma unroll
        for (int i = 0; i < 4; ++i)
            *(bf16x8*)(dstp + i * 512) = cur[i];
        // issue next K-step's loads NOW; they stay in flight across LBAR
        if (kt < 7) {
            #pragma unroll
            for (int i = 0; i < 4; ++i)
                nxt[i] = *(const bf16x8*)(srcp[i] + (size_t)(kt + 1) * sstep);
        }
        LBAR();                                  // ds_writes visible
        bf16x8 af[4], bf[4];
        #pragma unroll
        for (int m = 0; m < 4; ++m) af[m] = *(const bf16x8*)(afp + m * 512);
        #pragma unroll
        for (int n = 0; n < 4; ++n) bf[n] = *(const bf16x8*)(bfp + n * 512);
        #pragma unroll
        for (int m = 0; m < 4; ++m)
            #pragma unroll
            for (int n = 0; n < 4; ++n)
                acc[m][n] = __builtin_amdgcn_mfma_f32_16x16x32_bf16(af[m], bf[n], acc[m][n], 0, 0, 0);
        LBAR();                                  // reads done; next write safe
        if (kt < 7) {
            #pragma unroll
            for (int i = 0; i < 4; ++i) cur[i] = nxt[i];
        }
    }

    if (!kvmode) {
        // q: shorts [0..255], 2B stores
        #pragma unroll
        for (int n = 0; n < 4; ++n) {
            int col = bx * 128 + (wc * 4 + n) * 16 + col16;
            float bb = bq[col];
            #pragma unroll
            for (int m = 0; m < 4; ++m) {
                int rbase = by * 128 + (wr * 4 + m) * 16 + quad * 4;
                #pragma unroll
                for (int r = 0; r < 4; ++r) {
                    int row = rbase + r;
                    if (row < N_PTS)
                        out[(size_t)row * 768 + col] = f2bf(acc[m][n][r] + bb);
                }
            }
        }
    } else {
        // kv: dword[128+col] = k | v<<16 (coalesced, no holes)
        unsigned int* out32 = (unsigned int*)out;
        #pragma unroll
        for (int cf = 0; cf < 2; ++cf) {
            int col = qd * 64 + (wc * 2 + cf) * 16 + col16;
            float bbk = bk[col], bbv = bv[col];
            #pragma unroll
            for (int m = 0; m < 4; ++m) {
                int rbase = by * 128 + (wr * 4 + m) * 16 + quad * 4;
                #pragma unroll
                for (int r = 0; r < 4; ++r) {
                    int row = rbase + r;
                    if (row < N_PTS) {
                        unsigned int kk = f2bf(acc[m][2 * cf][r] + bbk);
                        unsigned int vv = f2bf(acc[m][2 * cf + 1][r] + bbv);
                        out32[(size_t)row * 384 + 128 + col] = kk | (vv << 16);
                    }
                }
            }
        }
    }
}

// ---------------------------------------------------------------------------
// Fused attention == r7 v3 structure EXACTLY (verified 212-214 us, absmax
// 0.03125 across r7/r10). At its structural floor for this decomposition.
// ---------------------------------------------------------------------------
#define D1S 72
#define PGS 66      // private geom row stride (dwords): 2-way banks on rd & wr
#define QKS 264
#define A1S 40
#define A2S 33

__global__ __launch_bounds__(256) void attn_mfma(
    const unsigned short* __restrict__ qkv,     // [N][768] q | kv-interleaved
    const float* __restrict__ q_pts, const float* __restrict__ s_pts,
    const int* __restrict__ nbr,
    const float* __restrict__ Wd1, const float* __restrict__ bd1,
    const float* __restrict__ bd2,
    const unsigned short* __restrict__ frags,
    const float* __restrict__ ba1, const float* __restrict__ ba2,
    float* __restrict__ out)
{
    __shared__ unsigned short s_d1[H * D1S];
    __shared__ float          s_pg[4 * H * PGS];   // wave-private geom tiles
    __shared__ unsigned short s_qk[H * QKS];
    __shared__ unsigned short s_a1[H * A1S];
    __shared__ float          s_a2[H * A2S];
    __shared__ float          s_rel[4][H][3];
    __shared__ int            s_idx[4][H];

    const int tid = threadIdx.x;
    const int lane = tid & 63, wave = tid >> 6;
    const int quad = lane >> 4, col = lane & 15;
    const int n0 = blockIdx.x * 4;
    const int c = tid;                 // == wave*64 + lane

    if (tid < 64) {
        int pp = tid >> 4, hh = tid & 15;
        int idx = nbr[(size_t)(n0 + pp) * H + hh];
        s_idx[pp][hh] = idx;
        #pragma unroll
        for (int x = 0; x < 3; ++x)
            s_rel[pp][hh][x] = s_pts[(size_t)idx * 3 + x] - q_pts[(size_t)(n0 + pp) * 3 + x];
    }

    const float w1x = Wd1[lane], w1y = Wd1[64 + lane], w1z = Wd1[128 + lane];
    const float b1 = bd1[lane];
    const float b2 = bd2[c];
    bf16x8 wd2f[2][4];
    #pragma unroll
    for (int t = 0; t < 4; ++t) {
        wd2f[0][t] = *(const bf16x8*)&frags[((size_t)((0 * 16 + wave * 4 + t) * 64 + lane)) * 8];
        wd2f[1][t] = *(const bf16x8*)&frags[((size_t)((1 * 16 + wave * 4 + t) * 64 + lane)) * 8];
    }
    bf16x8 wa1f[8];
    bf16x8 wa2f = {0,0,0,0,0,0,0,0};
    if (wave < 2) {
        #pragma unroll
        for (int kt = 0; kt < 8; ++kt)
            wa1f[kt] = *(const bf16x8*)&frags[16384 + ((size_t)((kt * 2 + wave) * 64 + lane)) * 8];
        wa2f = *(const bf16x8*)&frags[24576 + ((size_t)(wave * 64 + lane)) * 8];
    }
    __syncthreads();

    float* pg = &s_pg[wave * (H * PGS)];

    for (int p = 0; p < 4; ++p) {
        const int n = n0 + p;

        // d1 = lrelu(rel @ Wd1 + bd1)  (cross-wave, needs the barrier below)
        #pragma unroll
        for (int pass = 0; pass < 4; ++pass) {
            int h = pass * 4 + wave;
            float v = b1 + s_rel[p][h][0] * w1x + s_rel[p][h][1] * w1y + s_rel[p][h][2] * w1z;
            s_d1[h * D1S + lane] = f2bf(fmaxf(v, 0.1f * v));
        }
        __syncthreads();

        // ---- issue all gathers now; no barrier until after they're consumed
        unsigned int u[H];
        #pragma unroll
        for (int h = 0; h < H; ++h)
            u[h] = *(const unsigned int*)&qkv[(size_t)s_idx[p][h] * 768 + 256 + 2 * c];
        float qf = bf2f(qkv[(size_t)s_idx[p][0] * 768 + c]);

        // geom = d1 @ Wd2 (16x64 @ 64x256) -> wave-private C-tile in LDS
        {
            bf16x8 ga = *(bf16x8*)&s_d1[col * D1S + quad * 8];
            bf16x8 gb = *(bf16x8*)&s_d1[col * D1S + 32 + quad * 8];
            #pragma unroll
            for (int t = 0; t < 4; ++t) {
                f32x4 acc = {0.f, 0.f, 0.f, 0.f};
                acc = __builtin_amdgcn_mfma_f32_16x16x32_bf16(ga, wd2f[0][t], acc, 0, 0, 0);
                acc = __builtin_amdgcn_mfma_f32_16x16x32_bf16(gb, wd2f[1][t], acc, 0, 0, 0);
                #pragma unroll
                for (int rr = 0; rr < 4; ++rr)
                    pg[(quad * 4 + rr) * PGS + t * 16 + col] = acc[rr];
            }
        }
        // same-wave ds_write -> ds_read: lgkmcnt only, NO __syncthreads here.

        // elementwise: consume gathered kv + private geom; build vg + qk
        float vg[H];
        #pragma unroll
        for (int h = 0; h < H; ++h) {
            float g = pg[h * PGS + lane] + b2;
            float nk = __uint_as_float(u[h] << 16);
            float nv = __uint_as_float(u[h] & 0xffff0000u);
            vg[h] = nv - g;
            float tq = qf - nk - g;
            s_qk[h * QKS + c] = f2bf(fmaxf(tq, 0.1f * tq));
        }
        __syncthreads();

        // a1 = lrelu(qk @ Wa1 + ba1) on waves 0,1
        if (wave < 2) {
            f32x4 acc = {0.f, 0.f, 0.f, 0.f};
            #pragma unroll
            for (int kt = 0; kt < 8; ++kt) {
                bf16x8 a = *(bf16x8*)&s_qk[col * QKS + kt * 32 + quad * 8];
                acc = __builtin_amdgcn_mfma_f32_16x16x32_bf16(a, wa1f[kt], acc, 0, 0, 0);
            }
            int j = wave * 16 + col;
            float bb = ba1[j];
            #pragma unroll
            for (int rr = 0; rr < 4; ++rr) {
                float v = acc[rr] + bb;
                s_a1[(quad * 4 + rr) * A1S + j] = f2bf(fmaxf(v, 0.1f * v));
            }
        }
        __syncthreads();

        // a2 = a1 @ Wa2 + ba2 on waves 0,1
        if (wave < 2) {
            bf16x8 aa = *(bf16x8*)&s_a1[col * A1S + quad * 8];
            f32x4 acc = {0.f, 0.f, 0.f, 0.f};
            acc = __builtin_amdgcn_mfma_f32_16x16x32_bf16(aa, wa2f, acc, 0, 0, 0);
            int j = wave * 16 + col;
            float bb = ba2[j];
            #pragma unroll
            for (int rr = 0; rr < 4; ++rr)
                s_a2[(quad * 4 + rr) * A2S + j] = acc[rr] + bb;
        }
        __syncthreads();

        // softmax over h, wave 0
        if (wave == 0) {
            int j = lane & 31, hb = (lane >> 5) * 8;
            float vals[8];
            float mx = -1e30f;
            #pragma unroll
            for (int i = 0; i < 8; ++i) {
                vals[i] = s_a2[(hb + i) * A2S + j];
                mx = fmaxf(mx, vals[i]);
            }
            mx = fmaxf(mx, __shfl_xor(mx, 32));
            float sum = 0.f;
            #pragma unroll
            for (int i = 0; i < 8; ++i) { vals[i] = __expf(vals[i] - mx); sum += vals[i]; }
            sum += __shfl_xor(sum, 32);
            float inv = 1.f / sum;
            #pragma unroll
            for (int i = 0; i < 8; ++i) s_a2[(hb + i) * A2S + j] = vals[i] * inv;
        }
        __syncthreads();

        // out[n][c] = sum_h vg[h] * attn[h][c>>3]
        float o = 0.f;
        const int aj = c >> 3;
        #pragma unroll
        for (int h = 0; h < H; ++h) o += vg[h] * s_a2[h * A2S + aj];
        out[(size_t)n * C + c] = o;
    }
}

// ---------------------------------------------------------------------------

extern "C" void kernel_launch(void* const* d_in, const int* in_sizes, int n_in,
                              void* d_out, int out_size, void* d_ws, size_t ws_size,
                              hipStream_t stream) {
    const float* q_pts   = (const float*)d_in[0];
    const float* s_pts   = (const float*)d_in[1];
    const float* s_feats = (const float*)d_in[2];
    const int*   nbr     = (const int*)d_in[3];
    const float* Wq  = (const float*)d_in[4];
    const float* bq  = (const float*)d_in[5];
    const float* Wk  = (const float*)d_in[6];
    const float* bk  = (const float*)d_in[7];
    const float* Wv  = (const float*)d_in[8];
    const float* bv  = (const float*)d_in[9];
    const float* Wd1 = (const float*)d_in[10];
    const float* bd1 = (const float*)d_in[11];
    const float* Wd2 = (const float*)d_in[12];
    const float* bd2 = (const float*)d_in[13];
    const float* Wa1 = (const float*)d_in[14];
    const float* ba1 = (const float*)d_in[15];
    const float* Wa2 = (const float*)d_in[16];
    const float* ba2 = (const float*)d_in[17];

    float* out = (float*)d_out;
    char* ws = (char*)d_ws;
    unsigned short* Afrag     = (unsigned short*)(ws);                 // 25.6 MB
    unsigned short* qkvb      = (unsigned short*)(ws + 25600000);      // 76.8 MB
    unsigned short* attnFrags = (unsigned short*)(ws + 102400000);     // 51.2 KB
    unsigned short* gemmFrags = (unsigned short*)(ws + 102451200);     // 384 KB

    prep_all<<<6359, 256, 0, stream>>>(s_feats, Wq, Wk, Wv, Wd2, Wa1, Wa2,
                                       Afrag, gemmFrags, attnFrags);

    dim3 g1(6, (N_PTS + 127) / 128);
    qkv_gemm_mfma<<<g1, 256, 0, stream>>>(Afrag, gemmFrags, bq, bk, bv, qkvb);

    attn_mfma<<<(N_PTS / 4), 256, 0, stream>>>(qkvb, q_pts, s_pts, nbr,
                                               Wd1, bd1, bd2, attnFrags,
                                               ba1, ba2, out);
}